// Round 2
// baseline (251.896 us; speedup 1.0000x reference)
//
#include <hip/hip_runtime.h>
#include <hip/hip_bf16.h>

// CINLayer: cin_out[b,f,d] = sum_{c,n} W[f,c,n] * xj[b,c,d] * x0[b,n,d]
//           cin_p_out[b,f] = sum_d cin_out[b,f,d]
// B=2048, C=64, N=64, D=64, F=128.
//
// R2 structure: A'[(b,d),(c,n)] = xj[b,c,d]*x0[b,n,d] formed IN REGISTERS
// (per-lane scalar xj times hoisted x0 fragment), MFMA accumulates K=4096
// directly into acc. W-frags stream L2->registers (no LDS), xj from global
// (L1-resident). ZERO barriers / ZERO LDS ops in the main loop.

typedef unsigned short u16;
typedef __attribute__((ext_vector_type(8))) short bf16x8;
typedef __attribute__((ext_vector_type(4))) float f32x4;

__device__ __forceinline__ u16 f2b(float f) {
  union { float f; unsigned u; } x; x.f = f;
  unsigned r = x.u + 0x7fffu + ((x.u >> 16) & 1u);   // RNE bf16
  return (u16)(r >> 16);
}
__device__ __forceinline__ u16 cvb(float f) {        // compiler pairs into v_cvt_pk_bf16_f32
  return __bfloat16_as_ushort(__float2bfloat16(f));
}

// ---- pre-pass: W f32 (F*C*N = 524288) -> bf16 in ws ----
__global__ __launch_bounds__(256) void wconv_kernel(const float* __restrict__ W,
                                                    u16* __restrict__ Wb) {
  int i = (blockIdx.x * 256 + threadIdx.x) * 8;
  const float4 a = *(const float4*)(W + i);
  const float4 b = *(const float4*)(W + i + 4);
  bf16x8 r;
  r[0] = (short)f2b(a.x); r[1] = (short)f2b(a.y);
  r[2] = (short)f2b(a.z); r[3] = (short)f2b(a.w);
  r[4] = (short)f2b(b.x); r[5] = (short)f2b(b.y);
  r[6] = (short)f2b(b.z); r[7] = (short)f2b(b.w);
  *(bf16x8*)(Wb + i) = r;
}

__global__ __launch_bounds__(256, 2) void cin_kernel(
    const float* __restrict__ xj, const float* __restrict__ x0,
    const u16* __restrict__ Wb, float* __restrict__ out, float* __restrict__ pout) {
  // x0T[bb][d][swz(col)] = x0[b0+bb][n][d], f32, 16B-chunk XOR swizzle
  __shared__ float x0T[2][64][64];

  const int t  = threadIdx.x;
  const int b0 = blockIdx.x * 2;

  // ---- one-time: transpose-stage x0 (f32) ----
  for (int bb = 0; bb < 2; ++bb) {
    const float* s0 = x0 + (size_t)(b0 + bb) * 4096;
#pragma unroll
    for (int p = 0; p < 4; ++p) {
      const int e = p * 1024 + t * 4;
      const int n = e >> 6, d0 = e & 63;
      const float4 v = *(const float4*)(s0 + e);
      const int ch = n >> 2, sub = n & 3;
      x0T[bb][d0 + 0][(((ch ^ (d0 + 0)) & 15) << 2) | sub] = v.x;
      x0T[bb][d0 + 1][(((ch ^ (d0 + 1)) & 15) << 2) | sub] = v.y;
      x0T[bb][d0 + 2][(((ch ^ (d0 + 2)) & 15) << 2) | sub] = v.z;
      x0T[bb][d0 + 3][(((ch ^ (d0 + 3)) & 15) << 2) | sub] = v.w;
    }
  }
  __syncthreads();

  const int wid = t >> 6, lane = t & 63;
  const int wr = wid >> 1, wc = wid & 1;        // wave batch-half / f-half
  const int lr = lane & 15, lg = lane >> 4;

  // ---- hoisted x0 A-fragments in f32: af4[mf][q] = x0[b][n=q*4..q*4+3 (+kk*32+lg*8)][d=mf*16+lr]
  f32x4 af4[4][4];
#pragma unroll
  for (int mf = 0; mf < 4; ++mf) {
    const int d = mf * 16 + lr;
#pragma unroll
    for (int q = 0; q < 4; ++q) {               // q = kk*2 + h; chunk = kk*8 + lg*2 + h
      const int ch = (q >> 1) * 8 + lg * 2 + (q & 1);
      af4[mf][q] = *(const f32x4*)&x0T[wr][d][((ch ^ d) & 15) << 2];
    }
  }

  f32x4 acc[4][4];
#pragma unroll
  for (int i = 0; i < 4; ++i)
#pragma unroll
    for (int j = 0; j < 4; ++j) acc[i][j] = (f32x4){0.f, 0.f, 0.f, 0.f};

  // W frag pointers: frag(nf,kk) at Wb + (wc*64+nf*16+lr)*4096 + c*64 + kk*32 + lg*8
  const u16* wbase = Wb + (size_t)(wc * 64 + lr) * 4096 + lg * 8;
  const float* xjp = xj + (size_t)(b0 + wr) * 4096;   // + c*64 + mf*16+lr

  bf16x8 wbuf[2][4][2];
  float  xjb[2][4];

  // prologue: load c=0 into buffer 0
#pragma unroll
  for (int nf = 0; nf < 4; ++nf)
#pragma unroll
    for (int kk = 0; kk < 2; ++kk)
      wbuf[0][nf][kk] = *(const bf16x8*)(wbase + nf * 65536 + kk * 32);
#pragma unroll
  for (int mf = 0; mf < 4; ++mf) xjb[0][mf] = xjp[mf * 16 + lr];

  auto body = [&](int c, int cur, int nxt) {
    const int cn = (c < 63) ? c + 1 : c;
    // prefetch next c (vmcnt overlap under compute)
#pragma unroll
    for (int nf = 0; nf < 4; ++nf)
#pragma unroll
      for (int kk = 0; kk < 2; ++kk)
        wbuf[nxt][nf][kk] = *(const bf16x8*)(wbase + nf * 65536 + cn * 64 + kk * 32);
#pragma unroll
    for (int mf = 0; mf < 4; ++mf) xjb[nxt][mf] = xjp[cn * 64 + mf * 16 + lr];

    // compute: form A' per mf, 8 MFMAs direct-accumulate
#pragma unroll
    for (int mf = 0; mf < 4; ++mf) {
      const float xf = xjb[cur][mf];
      bf16x8 ap[2];
#pragma unroll
      for (int kk = 0; kk < 2; ++kk) {
        const f32x4 pa = xf * af4[mf][kk * 2 + 0];
        const f32x4 pb = xf * af4[mf][kk * 2 + 1];
        bf16x8 r;
        r[0] = (short)cvb(pa[0]); r[1] = (short)cvb(pa[1]);
        r[2] = (short)cvb(pa[2]); r[3] = (short)cvb(pa[3]);
        r[4] = (short)cvb(pb[0]); r[5] = (short)cvb(pb[1]);
        r[6] = (short)cvb(pb[2]); r[7] = (short)cvb(pb[3]);
        ap[kk] = r;
      }
#pragma unroll
      for (int kk = 0; kk < 2; ++kk)
#pragma unroll
        for (int nf = 0; nf < 4; ++nf)
          acc[mf][nf] = __builtin_amdgcn_mfma_f32_16x16x32_bf16(
              ap[kk], wbuf[cur][nf][kk], acc[mf][nf], 0, 0, 0);
    }
  };

  for (int cc = 0; cc < 32; ++cc) {   // explicit 2x unroll: buffer idx compile-time
    body(2 * cc + 0, 0, 1);
    body(2 * cc + 1, 1, 0);
  }

  // ---- epilogue: D frag col = lane&15 (f), row = (lane>>4)*4 + reg (d) ----
  const int b = b0 + wr;
  float psum[4] = {0.f, 0.f, 0.f, 0.f};
#pragma unroll
  for (int mf = 0; mf < 4; ++mf) {
    const int d = mf * 16 + lg * 4;
#pragma unroll
    for (int nf = 0; nf < 4; ++nf) {
      const int f = wc * 64 + nf * 16 + lr;
      const f32x4 v = acc[mf][nf];
      *(f32x4*)(out + (size_t)b * (128 * 64) + (size_t)f * 64 + d) = v;
      psum[nf] += v[0] + v[1] + v[2] + v[3];
    }
  }
#pragma unroll
  for (int nf = 0; nf < 4; ++nf) {
    float s = psum[nf];
    s += __shfl_xor(s, 16, 64);
    s += __shfl_xor(s, 32, 64);
    if (lg == 0) pout[(size_t)b * 128 + wc * 64 + nf * 16 + lr] = s;
  }
}

extern "C" void kernel_launch(void* const* d_in, const int* in_sizes, int n_in,
                              void* d_out, int out_size, void* d_ws, size_t ws_size,
                              hipStream_t stream) {
  const float* xj = (const float*)d_in[0];   // (2048, 64, 64)
  const float* x0 = (const float*)d_in[1];   // (2048, 64, 64)
  const float* W  = (const float*)d_in[2];   // (128, 64, 64)
  float* out  = (float*)d_out;               // cin_out (2048,128,64) then cin_p_out (2048,128)
  float* pout = out + (size_t)2048 * 128 * 64;
  u16* Wb = (u16*)d_ws;                      // 1 MiB bf16 copy of W

  wconv_kernel<<<256, 256, 0, stream>>>(W, Wb);
  cin_kernel<<<1024, 256, 0, stream>>>(xj, x0, Wb, out, pout);
}

// Round 3
// 153.448 us; speedup vs baseline: 1.6416x; 1.6416x over previous
//
#include <hip/hip_runtime.h>

// CINLayer: cin_out[b,f,d] = sum_{c,n} W[f,c,n] * xj[b,c,d] * x0[b,n,d]
//           cin_p_out[b,f] = sum_d cin_out[b,f,d]
// B=2048, C=64, N=64, D=64, F=128.
//
// R3: A'[(b,d),n] = xj[b,c,d]*x0[b,n,d] formed in regs via v_pk_mul_f16 from
// hoisted f16 x0-fragments; MFMA 32x32x16_f16 accumulates over c directly.
// BM=256 (4 batches) x BN=128, 8 waves. W tile (16KB/c) LDS-double-buffered
// via global_load_lds(16B) with XOR chunk swizzle (pre-swizzled global src,
// linear LDS dest). One barrier per c. MFMA:LDS cyc ratio ~1024:640.

typedef _Float16 f16;
typedef __attribute__((ext_vector_type(8))) _Float16 half8;
typedef __attribute__((ext_vector_type(16))) float f32x16;
typedef __attribute__((ext_vector_type(4))) float f32x4;

#define GLOAD16(g, l) __builtin_amdgcn_global_load_lds( \
    (const __attribute__((address_space(1))) void*)(g), \
    (__attribute__((address_space(3))) void*)(l), 16, 0, 0)

// ---- pre-pass: W f32 (F*C*N = 524288) -> f16 in ws ----
__global__ __launch_bounds__(256) void wconv_kernel(const float* __restrict__ W,
                                                    f16* __restrict__ Wh) {
  int i = (blockIdx.x * 256 + threadIdx.x) * 8;
  const float4 a = *(const float4*)(W + i);
  const float4 b = *(const float4*)(W + i + 4);
  half8 r;
  r[0] = (f16)a.x; r[1] = (f16)a.y; r[2] = (f16)a.z; r[3] = (f16)a.w;
  r[4] = (f16)b.x; r[5] = (f16)b.y; r[6] = (f16)b.z; r[7] = (f16)b.w;
  *(half8*)(Wh + i) = r;
}

__global__ __launch_bounds__(512, 2) void cin_kernel(
    const float* __restrict__ xj, const float* __restrict__ x0,
    const f16* __restrict__ Wh, float* __restrict__ out,
    float* __restrict__ pout) {
  // x0T[bb*4096 + d*64 + ((n>>3)^(d&7))*8 + (n&7)] = f16(x0[b0+bb][n][d])
  __shared__ f16 x0T[4 * 4096];   // 32 KB
  // Wt[buf*8192 + f*64 + ch*8 ..] : LDS slot (f,ch) holds W chunk (ch^(f&7))
  __shared__ f16 Wt[2 * 8192];    // 32 KB double buffer

  const int t = threadIdx.x;
  const int wid = t >> 6, lane = t & 63;
  const int b0 = blockIdx.x * 4;

  // ---- prologue: stage W(c=0) into buf0 (inverse-swizzled source) ----
#pragma unroll
  for (int p = 0; p < 2; ++p) {
    const int s = p * 512 + wid * 64 + lane;       // 16B slot in tile
    const int f = s >> 3, ch = s & 7;
    const f16* gp = Wh + (size_t)f * 4096 + ((ch ^ (f & 7)) << 3);
    f16* lp = Wt + (p * 512 + wid * 64) * 8;       // wave-uniform, linear dest
    GLOAD16(gp, lp);
  }

  // ---- stage x0T: transpose + f16 + chunk swizzle (one-time) ----
  // thread t: n = lane, d-chunk = wid  -> wave writes spread over all banks
#pragma unroll
  for (int bb = 0; bb < 4; ++bb) {
    const float* s0 = x0 + (size_t)(b0 + bb) * 4096;
    const int n = lane, d0 = wid * 8;
    const float4 va = *(const float4*)(s0 + n * 64 + d0);
    const float4 vb = *(const float4*)(s0 + n * 64 + d0 + 4);
    const int chb = n >> 3, sub = n & 7;
#pragma unroll
    for (int j = 0; j < 8; ++j) {
      const float v = (j < 4) ? ((const float*)&va)[j] : ((const float*)&vb)[j - 4];
      const int d = d0 + j;
      x0T[bb * 4096 + d * 64 + ((chb ^ (d & 7)) << 3) + sub] = (f16)v;
    }
  }
  __syncthreads();

  const int wc = wid & 1, bb = wid >> 1;   // wave: f-half wc, batch bb
  const int lr = lane & 31, hi = lane >> 5;

  // ---- hoisted x0 A-fragments (f16): af[mf][kk][i] = x0[b][kk*16+hi*8+i][mf*32+lr]
  half8 af[2][4];
#pragma unroll
  for (int mf = 0; mf < 2; ++mf) {
    const int d = mf * 32 + lr;
#pragma unroll
    for (int kk = 0; kk < 4; ++kk)
      af[mf][kk] = *(const half8*)&x0T[bb * 4096 + d * 64 +
                                       (((kk * 2 + hi) ^ (d & 7)) << 3)];
  }

  f32x16 acc[2][2] = {};

  const float* xjg = xj + (size_t)(b0 + bb) * 4096 + lr;   // + c*64 (+32 mf=1)
  float xjc0 = xjg[0], xjc1 = xjg[32];

  for (int c = 0; c < 64; ++c) {
    const int buf = c & 1;
    if (c < 63) {   // stage W(c+1) into other buffer (overlaps with compute)
#pragma unroll
      for (int p = 0; p < 2; ++p) {
        const int s = p * 512 + wid * 64 + lane;
        const int f = s >> 3, ch = s & 7;
        const f16* gp = Wh + (size_t)f * 4096 + (c + 1) * 64 + ((ch ^ (f & 7)) << 3);
        f16* lp = Wt + (buf ^ 1) * 8192 + (p * 512 + wid * 64) * 8;
        GLOAD16(gp, lp);
      }
    }
    float xjn0 = 0.f, xjn1 = 0.f;
    if (c < 63) { xjn0 = xjg[(c + 1) * 64]; xjn1 = xjg[(c + 1) * 64 + 32]; }

    // B-fragments: bf[nf][kk][i] = W[f=wc*64+nf*32+lr][c][kk*16+hi*8+i]
    half8 bf[2][4];
#pragma unroll
    for (int nf = 0; nf < 2; ++nf) {
      const int f = wc * 64 + nf * 32 + lr;
#pragma unroll
      for (int kk = 0; kk < 4; ++kk)
        bf[nf][kk] = *(const half8*)&Wt[buf * 8192 + f * 64 +
                                        (((kk * 2 + hi) ^ (f & 7)) << 3)];
    }

    // A' = xj*x0 (v_pk_mul_f16), 16 MFMAs direct-accumulate
    const f16 xh0 = (f16)xjc0, xh1 = (f16)xjc1;
#pragma unroll
    for (int kk = 0; kk < 4; ++kk) {
      const half8 ap0 = af[0][kk] * xh0;
      const half8 ap1 = af[1][kk] * xh1;
      acc[0][0] = __builtin_amdgcn_mfma_f32_32x32x16_f16(ap0, bf[0][kk], acc[0][0], 0, 0, 0);
      acc[0][1] = __builtin_amdgcn_mfma_f32_32x32x16_f16(ap0, bf[1][kk], acc[0][1], 0, 0, 0);
      acc[1][0] = __builtin_amdgcn_mfma_f32_32x32x16_f16(ap1, bf[0][kk], acc[1][0], 0, 0, 0);
      acc[1][1] = __builtin_amdgcn_mfma_f32_32x32x16_f16(ap1, bf[1][kk], acc[1][1], 0, 0, 0);
    }
    xjc0 = xjn0; xjc1 = xjn1;
    __syncthreads();
  }

  // ---- epilogue: D layout col=lane&31 (f), row=(reg&3)+8*(reg>>2)+4*hi (d) ----
  const int b = b0 + bb;
  float* ob = out + (size_t)b * 8192;
  float psum[2] = {0.f, 0.f};
#pragma unroll
  for (int mf = 0; mf < 2; ++mf) {
#pragma unroll
    for (int nf = 0; nf < 2; ++nf) {
      const int f = wc * 64 + nf * 32 + lr;
      const f32x16 v = acc[mf][nf];
      float s = 0.f;
#pragma unroll
      for (int q = 0; q < 4; ++q) {
        f32x4 vv = { v[4 * q], v[4 * q + 1], v[4 * q + 2], v[4 * q + 3] };
        *(f32x4*)(ob + f * 64 + mf * 32 + q * 8 + hi * 4) = vv;
        s += vv[0] + vv[1] + vv[2] + vv[3];
      }
      psum[nf] += s;
    }
  }
#pragma unroll
  for (int nf = 0; nf < 2; ++nf) {
    float s = psum[nf];
    s += __shfl_xor(s, 32, 64);
    if (hi == 0) pout[(size_t)b * 128 + wc * 64 + nf * 32 + lr] = s;
  }
}

extern "C" void kernel_launch(void* const* d_in, const int* in_sizes, int n_in,
                              void* d_out, int out_size, void* d_ws, size_t ws_size,
                              hipStream_t stream) {
  const float* xj = (const float*)d_in[0];   // (2048, 64, 64)
  const float* x0 = (const float*)d_in[1];   // (2048, 64, 64)
  const float* W  = (const float*)d_in[2];   // (128, 64, 64)
  float* out  = (float*)d_out;               // cin_out (2048,128,64), cin_p_out (2048,128)
  float* pout = out + (size_t)2048 * 128 * 64;
  f16* Wh = (f16*)d_ws;                      // 1 MiB f16 copy of W

  wconv_kernel<<<256, 256, 0, stream>>>(W, Wh);
  cin_kernel<<<512, 512, 0, stream>>>(xj, x0, Wh, out, pout);
}

// Round 4
// 146.136 us; speedup vs baseline: 1.7237x; 1.0500x over previous
//
#include <hip/hip_runtime.h>

// CINLayer: cin_out[b,f,d] = sum_{c,n} W[f,c,n] * xj[b,c,d] * x0[b,n,d]
//           cin_p_out[b,f] = sum_d cin_out[b,f,d]
// B=2048, C=64, N=64, D=64, F=128.
//
// R4: wave = 2 batches x 32 f (mf=4, nf=1) -> LDS B-frag traffic halved.
// W pre-scattered into fragment-major f16 (d_ws): per c-slice, 1024 contiguous
// 16B slots in exact MFMA-fragment order -> global_load_lds dest lane-linear,
// ds_read_b128 at base+lane*16 conflict-free. 4-buffer counted-vmcnt pipeline:
// s_waitcnt vmcnt(8) + raw s_barrier per iter, stages c+1/c+2 stay in flight.

typedef _Float16 f16;
typedef __attribute__((ext_vector_type(8))) _Float16 half8;
typedef __attribute__((ext_vector_type(16))) float f32x16;
typedef __attribute__((ext_vector_type(4))) float f32x4;

#define GLOAD16(g, l) __builtin_amdgcn_global_load_lds( \
    (const __attribute__((address_space(1))) void*)(g), \
    (__attribute__((address_space(3))) void*)(l), 16, 0, 0)

// ---- pre-pass: scatter W f32 -> f16 fragment-major ----
// Wb elem layout: [c][slot][8], slot = (g*4+kk)*64 + hi*32 + lr
//   holds W[f=g*32+lr][c][kk*16+hi*8 .. +8]
__global__ __launch_bounds__(256) void wscat_kernel(const float* __restrict__ W,
                                                    f16* __restrict__ Wb) {
  const int tid = blockIdx.x * 256 + threadIdx.x;   // 65536 threads
  const int c = tid >> 10, s = tid & 1023;
  const int gk = s >> 6, ln = s & 63;
  const int g = gk >> 2, kk = gk & 3, hi = ln >> 5, lr = ln & 31;
  const int f = g * 32 + lr, n0 = kk * 16 + hi * 8;
  const float* src = W + (size_t)f * 4096 + c * 64 + n0;
  const float4 a = *(const float4*)src;
  const float4 b = *(const float4*)(src + 4);
  half8 r;
  r[0] = (f16)a.x; r[1] = (f16)a.y; r[2] = (f16)a.z; r[3] = (f16)a.w;
  r[4] = (f16)b.x; r[5] = (f16)b.y; r[6] = (f16)b.z; r[7] = (f16)b.w;
  *(half8*)(Wb + (size_t)c * 8192 + s * 8) = r;
}

__global__ __launch_bounds__(512, 2) void cin_kernel(
    const float* __restrict__ xj, const float* __restrict__ x0,
    const f16* __restrict__ Wb, float* __restrict__ out,
    float* __restrict__ pout) {
  // x0T[bb*4096 + d*64 + ((n>>3)^(d&7))*8 + (n&7)] = f16(x0[b0+bb][n][d])
  __shared__ f16 x0T[4 * 4096];   // 32 KB
  __shared__ f16 Wt[4 * 8192];    // 64 KB: 4 bufs x 1024 slots x 8 f16

  const int t = threadIdx.x;
  const int wid = t >> 6, lane = t & 63;
  const int b0 = blockIdx.x * 4;

  // ---- one-time: transpose-stage x0 as f16 (chunk-swizzled) ----
#pragma unroll
  for (int bb = 0; bb < 4; ++bb) {
    const float* s0 = x0 + (size_t)(b0 + bb) * 4096;
    const int n = lane, d0 = wid * 8;
    const float4 va = *(const float4*)(s0 + n * 64 + d0);
    const float4 vb = *(const float4*)(s0 + n * 64 + d0 + 4);
    const int chb = n >> 3, sub = n & 7;
#pragma unroll
    for (int j = 0; j < 8; ++j) {
      const float v = (j < 4) ? ((const float*)&va)[j] : ((const float*)&vb)[j - 4];
      const int d = d0 + j;
      x0T[bb * 4096 + d * 64 + (((chb) ^ (d & 7)) << 3) + sub] = (f16)v;
    }
  }
  __syncthreads();   // full drain OK: before any W prefetch is issued

  // wave mapping: wg = f-group (f = wg*32+lr), bp = batch pair
  const int wg = wid & 3, bp = wid >> 2;
  const int lr = lane & 31, hi = lane >> 5;

  // ---- hoisted x0 A-fragments: af[mf][kk]; mf = (bb'<<1)|dh ----
  // batch = b0+bp*2+bb', d = dh*32+lr; elems n = kk*16+hi*8+j
  half8 af[4][4];
#pragma unroll
  for (int mf = 0; mf < 4; ++mf) {
    const int bb = bp * 2 + (mf >> 1);
    const int d = (mf & 1) * 32 + lr;
#pragma unroll
    for (int kk = 0; kk < 4; ++kk)
      af[mf][kk] = *(const half8*)&x0T[bb * 4096 + d * 64 +
                                       (((kk * 2 + hi) ^ (d & 7)) << 3)];
  }

  f32x16 acc[4] = {};

  // stage addressing: thread stages slots (wid+8p)*64+lane, p in {0,1}
  const f16* wsrc = Wb + ((size_t)wid * 64 + lane) * 8;     // + c*8192 + p*4096
  f16* wdst = Wt + ((size_t)wid * 64 + lane) * 8;           // + buf*8192 + p*4096
  // xj: lane needs xj[b0+bp*2+bb'][c][dh*32+lr]
  const float* xjp = xj + (size_t)(b0 + bp * 2) * 4096 + lr;

  // ---- prologue: stage c=0,1,2; load xj(0) ----
#pragma unroll
  for (int cc = 0; cc < 3; ++cc) {
    GLOAD16(wsrc + (size_t)cc * 8192, wdst + cc * 8192);
    GLOAD16(wsrc + (size_t)cc * 8192 + 4096, wdst + cc * 8192 + 4096);
  }
  float xc0 = xjp[0], xc1 = xjp[32], xc2 = xjp[4096], xc3 = xjp[4096 + 32];

#pragma unroll 1
  for (int c = 0; c < 64; ++c) {
    // stage(c) guaranteed landed: worst-case queue s(c)2+s(c+1)2+s(c+2)2+xj(c)4=10
    // -> vmcnt(8) retires the 2 oldest (= s(c)); s(c+1),s(c+2),xj stay in flight.
    asm volatile("s_waitcnt vmcnt(8)" ::: "memory");
    __builtin_amdgcn_s_barrier();
    __builtin_amdgcn_sched_barrier(0);

    // B-frags: conflict-free contiguous reads at base + lane*16
    const f16* wb = Wt + (c & 3) * 8192 + wg * 2048;
    half8 bf0 = *(const half8*)&wb[0 * 512 + lane * 8];
    half8 bf1 = *(const half8*)&wb[1 * 512 + lane * 8];
    half8 bf2 = *(const half8*)&wb[2 * 512 + lane * 8];
    half8 bf3 = *(const half8*)&wb[3 * 512 + lane * 8];

    // stage c+3 (clamped; dummy re-stages land in dead buffers)
    const int cs = (c < 61) ? c + 3 : 63;
    GLOAD16(wsrc + (size_t)cs * 8192, wdst + ((c + 3) & 3) * 8192);
    GLOAD16(wsrc + (size_t)cs * 8192 + 4096, wdst + ((c + 3) & 3) * 8192 + 4096);

    // xj prefetch (c+1, clamped)
    const int cx = (c < 63) ? c + 1 : 63;
    const float xn0 = xjp[cx * 64], xn1 = xjp[cx * 64 + 32];
    const float xn2 = xjp[4096 + cx * 64], xn3 = xjp[4096 + cx * 64 + 32];

    // A' = xj * x0 (v_pk_mul_f16), 16 MFMAs direct-accumulate
    const f16 xh0 = (f16)xc0, xh1 = (f16)xc1, xh2 = (f16)xc2, xh3 = (f16)xc3;
#pragma unroll
    for (int kk = 0; kk < 4; ++kk) {
      const half8 bfv = (kk == 0) ? bf0 : (kk == 1) ? bf1 : (kk == 2) ? bf2 : bf3;
      acc[0] = __builtin_amdgcn_mfma_f32_32x32x16_f16(af[0][kk] * xh0, bfv, acc[0], 0, 0, 0);
      acc[1] = __builtin_amdgcn_mfma_f32_32x32x16_f16(af[1][kk] * xh1, bfv, acc[1], 0, 0, 0);
      acc[2] = __builtin_amdgcn_mfma_f32_32x32x16_f16(af[2][kk] * xh2, bfv, acc[2], 0, 0, 0);
      acc[3] = __builtin_amdgcn_mfma_f32_32x32x16_f16(af[3][kk] * xh3, bfv, acc[3], 0, 0, 0);
    }
    xc0 = xn0; xc1 = xn1; xc2 = xn2; xc3 = xn3;
  }

  // ---- epilogue: D layout col=lane&31 (f), row=(reg&3)+8*(reg>>2)+4*hi (d) ----
  const int fcol = wg * 32 + lr;
  float ps[4];
#pragma unroll
  for (int mf = 0; mf < 4; ++mf) {
    const int b = b0 + bp * 2 + (mf >> 1);
    float* ob = out + (size_t)b * 8192 + (size_t)fcol * 64 + (mf & 1) * 32;
    const f32x16 v = acc[mf];
    float s = 0.f;
#pragma unroll
    for (int q = 0; q < 4; ++q) {
      f32x4 vv = { v[4 * q], v[4 * q + 1], v[4 * q + 2], v[4 * q + 3] };
      *(f32x4*)(ob + q * 8 + hi * 4) = vv;
      s += vv[0] + vv[1] + vv[2] + vv[3];
    }
    ps[mf] = s;
  }
  float pA = ps[0] + ps[1];   // batch b0+bp*2
  float pB = ps[2] + ps[3];   // batch b0+bp*2+1
  pA += __shfl_xor(pA, 32, 64);
  pB += __shfl_xor(pB, 32, 64);
  if (hi == 0) {
    pout[(size_t)(b0 + bp * 2) * 128 + fcol] = pA;
    pout[(size_t)(b0 + bp * 2 + 1) * 128 + fcol] = pB;
  }
}

extern "C" void kernel_launch(void* const* d_in, const int* in_sizes, int n_in,
                              void* d_out, int out_size, void* d_ws, size_t ws_size,
                              hipStream_t stream) {
  const float* xj = (const float*)d_in[0];   // (2048, 64, 64)
  const float* x0 = (const float*)d_in[1];   // (2048, 64, 64)
  const float* W  = (const float*)d_in[2];   // (128, 64, 64)
  float* out  = (float*)d_out;               // cin_out (2048,128,64), cin_p_out (2048,128)
  float* pout = out + (size_t)2048 * 128 * 64;
  f16* Wb = (f16*)d_ws;                      // 1 MiB fragment-major f16 W

  wscat_kernel<<<256, 256, 0, stream>>>(W, Wb);
  cin_kernel<<<512, 512, 0, stream>>>(xj, x0, Wb, out, pout);
}